// Round 3
// baseline (143.906 us; speedup 1.0000x reference)
//
#include <hip/hip_runtime.h>

#define NTHREADS 256
// Each thread: 8 triples = 24 floats = 6 float4 per input stream.
#define TRIP_PER_THREAD 8
#define F4_PER_THREAD 6

__device__ __forceinline__ float wave_reduce(float v) {
    #pragma unroll
    for (int off = 32; off > 0; off >>= 1) v += __shfl_down(v, off, 64);
    return v;
}

__device__ __forceinline__ float block_reduce(float v) {
    v = wave_reduce(v);
    __shared__ float smem[NTHREADS / 64];
    const int lane = threadIdx.x & 63;
    const int wave = threadIdx.x >> 6;
    if (lane == 0) smem[wave] = v;
    __syncthreads();
    float s = 0.f;
    if (threadIdx.x == 0) {
        #pragma unroll
        for (int w = 0; w < NTHREADS / 64; ++w) s += smem[w];
    }
    return s;
}

// MLP-maximizing: all 12 dwordx4 loads issued before any use; launch_bounds
// (256,4) permits up to 128 VGPRs so the compiler can keep them all in flight.
__global__ __launch_bounds__(NTHREADS, 4) void dis_partial_kernel(
    const float4* __restrict__ p4, const float4* __restrict__ t4,
    const float* __restrict__ pred, const float* __restrict__ targ,
    float* __restrict__ partials, int nchunk, int ntrip) {
    const int t = blockIdx.x * NTHREADS + threadIdx.x;
    float acc0 = 0.f, acc1 = 0.f;

    if (t < nchunk) {
        alignas(16) float pv[24];
        alignas(16) float tv[24];
        const int base = F4_PER_THREAD * t;
        #pragma unroll
        for (int j = 0; j < F4_PER_THREAD; ++j)
            ((float4*)pv)[j] = p4[base + j];
        #pragma unroll
        for (int j = 0; j < F4_PER_THREAD; ++j)
            ((float4*)tv)[j] = t4[base + j];

        #pragma unroll
        for (int k = 0; k < TRIP_PER_THREAD; k += 2) {
            float dx0 = pv[3 * k + 0] - tv[3 * k + 0];
            float dy0 = pv[3 * k + 1] - tv[3 * k + 1];
            float dz0 = pv[3 * k + 2] - tv[3 * k + 2];
            float dx1 = pv[3 * k + 3] - tv[3 * k + 3];
            float dy1 = pv[3 * k + 4] - tv[3 * k + 4];
            float dz1 = pv[3 * k + 5] - tv[3 * k + 5];
            acc0 += sqrtf(dx0 * dx0 + dy0 * dy0 + dz0 * dz0);
            acc1 += sqrtf(dx1 * dx1 + dy1 * dy1 + dz1 * dz1);
        }
    }

    // Generic scalar tail (empty for B=262144: 24 | n exactly).
    for (int j = nchunk * TRIP_PER_THREAD + t; j < ntrip;
         j += gridDim.x * NTHREADS) {
        const float dx = pred[3 * j + 0] - targ[3 * j + 0];
        const float dy = pred[3 * j + 1] - targ[3 * j + 1];
        const float dz = pred[3 * j + 2] - targ[3 * j + 2];
        acc0 += sqrtf(dx * dx + dy * dy + dz * dz);
    }

    const float s = block_reduce(acc0 + acc1);
    if (threadIdx.x == 0) partials[blockIdx.x] = s;
}

__global__ __launch_bounds__(NTHREADS) void dis_finalize_kernel(
    const float* __restrict__ partials, float* __restrict__ out,
    int nblocks, float scale) {
    float acc = 0.f;
    for (int i = threadIdx.x; i < nblocks; i += NTHREADS) acc += partials[i];
    const float s = block_reduce(acc);
    if (threadIdx.x == 0) out[0] = s * scale;  // full overwrite of poisoned d_out
}

extern "C" void kernel_launch(void* const* d_in, const int* in_sizes, int n_in,
                              void* d_out, int out_size, void* d_ws, size_t ws_size,
                              hipStream_t stream) {
    const float* pred = (const float*)d_in[0];
    const float* targ = (const float*)d_in[1];
    float* out = (float*)d_out;
    float* partials = (float*)d_ws;  // one float per block, each block owns its slot

    const int n = in_sizes[0];                       // B * 63 = 16,515,072
    const int ntrip = n / 3;                         // 5,505,024 joint distances
    const int nchunk = n / (3 * TRIP_PER_THREAD);    // 688,128 threads (exact)
    const int nblocks = (nchunk + NTHREADS - 1) / NTHREADS;  // 2688
    const float scale = 1.0f / (float)ntrip;

    dis_partial_kernel<<<nblocks, NTHREADS, 0, stream>>>(
        (const float4*)pred, (const float4*)targ, pred, targ, partials,
        nchunk, ntrip);
    dis_finalize_kernel<<<1, NTHREADS, 0, stream>>>(partials, out, nblocks, scale);
}